// Round 4
// baseline (446.428 us; speedup 1.0000x reference)
//
#include <hip/hip_runtime.h>
#include <math.h>

#define NEG_SLOPE 0.01f
#define BSH 5                 // 32 nodes per bucket
#define BSZ (1 << BSH)

// ---------------- CSR build ----------------

__global__ void hist_kernel(const int* __restrict__ dst, int* __restrict__ counts, int E) {
    int e = blockIdx.x * 256 + threadIdx.x;
    if (e < E) atomicAdd(&counts[dst[e]], 1);
}

// ---- multi-block exclusive scan of counts[0..n) -> offsets/cursor; offsets[n]=total ----

__global__ void scan_bsum(const int* __restrict__ counts, int* __restrict__ bsums, int n) {
    int t = threadIdx.x;
    int i0 = blockIdx.x * 1024 + t * 4;
    int4 c;
    if (i0 + 3 < n) {
        c = *reinterpret_cast<const int4*>(counts + i0);
    } else {
        c.x = (i0 + 0 < n) ? counts[i0 + 0] : 0;
        c.y = (i0 + 1 < n) ? counts[i0 + 1] : 0;
        c.z = (i0 + 2 < n) ? counts[i0 + 2] : 0;
        c.w = (i0 + 3 < n) ? counts[i0 + 3] : 0;
    }
    int s = c.x + c.y + c.z + c.w;
#pragma unroll
    for (int d = 32; d > 0; d >>= 1) s += __shfl_down(s, d);
    __shared__ int wtot[4];
    if ((t & 63) == 0) wtot[t >> 6] = s;
    __syncthreads();
    if (t == 0) bsums[blockIdx.x] = wtot[0] + wtot[1] + wtot[2] + wtot[3];
}

__global__ void scan_bsums(int* __restrict__ bsums, int* __restrict__ offsets, int nb, int n) {
    __shared__ int lds[128];
    int t = threadIdx.x;
    int v = (t < nb) ? bsums[t] : 0;
    lds[t] = v;
    __syncthreads();
    for (int d = 1; d < 128; d <<= 1) {
        int u = (t >= d) ? lds[t - d] : 0;
        __syncthreads();
        lds[t] += u;
        __syncthreads();
    }
    if (t < nb) bsums[t] = lds[t] - v;   // exclusive block base
    if (t == 127) offsets[n] = lds[127]; // total
}

__global__ void scan_write(const int* __restrict__ counts, const int* __restrict__ bbase,
                           int* __restrict__ offsets, int* __restrict__ cursor, int n) {
    int t = threadIdx.x;
    int lane = t & 63, wid = t >> 6;
    int i0 = blockIdx.x * 1024 + t * 4;
    int4 c;
    if (i0 + 3 < n) {
        c = *reinterpret_cast<const int4*>(counts + i0);
    } else {
        c.x = (i0 + 0 < n) ? counts[i0 + 0] : 0;
        c.y = (i0 + 1 < n) ? counts[i0 + 1] : 0;
        c.z = (i0 + 2 < n) ? counts[i0 + 2] : 0;
        c.w = (i0 + 3 < n) ? counts[i0 + 3] : 0;
    }
    int s = c.x + c.y + c.z + c.w;
    int inc = s;
#pragma unroll
    for (int d = 1; d < 64; d <<= 1) {
        int v = __shfl_up(inc, d);
        if (lane >= d) inc += v;
    }
    __shared__ int wtot[4];
    if (lane == 63) wtot[wid] = inc;
    __syncthreads();
    int wbase = 0;
    for (int i = 0; i < wid; ++i) wbase += wtot[i];
    int excl = bbase[blockIdx.x] + wbase + inc - s;
    int o0 = excl, o1 = o0 + c.x, o2 = o1 + c.y, o3 = o2 + c.z;
    if (i0 + 3 < n) {
        int4 o = make_int4(o0, o1, o2, o3);
        *reinterpret_cast<int4*>(offsets + i0) = o;
        *reinterpret_cast<int4*>(cursor + i0)  = o;
    } else {
        if (i0 + 0 < n) { offsets[i0 + 0] = o0; cursor[i0 + 0] = o0; }
        if (i0 + 1 < n) { offsets[i0 + 1] = o1; cursor[i0 + 1] = o1; }
        if (i0 + 2 < n) { offsets[i0 + 2] = o2; cursor[i0 + 2] = o2; }
        if (i0 + 3 < n) { offsets[i0 + 3] = o3; cursor[i0 + 3] = o3; }
    }
}

// bucket cursors init: bcursor[b] = offsets[b*BSZ]
__global__ void binit_kernel(const int* __restrict__ offsets, int* __restrict__ bcursor, int nbk) {
    int b = blockIdx.x * 256 + threadIdx.x;
    if (b < nbk) bcursor[b] = offsets[b << BSH];
}

// Pass A: scatter edges into bucket order. Record packs (w bits, src | dlocal<<18).
__global__ void binA_kernel(const int* __restrict__ src, const int* __restrict__ dst,
                            const float* __restrict__ w, int* __restrict__ bcursor,
                            int2* __restrict__ binned, int E) {
    int e = blockIdx.x * 256 + threadIdx.x;
    if (e < E) {
        int d = dst[e];
        int b = d >> BSH;
        int pos = atomicAdd(&bcursor[b], 1);
        int2 r;
        r.x = __float_as_int(w[e]);
        r.y = src[e] | ((d & (BSZ - 1)) << 18);
        binned[pos] = r;
    }
}

// Pass B: one block per bucket; exact per-node placement within an L2-resident window.
__global__ void binB_kernel(const int* __restrict__ offsets, int* __restrict__ ncursor,
                            const int2* __restrict__ binned, int2* __restrict__ csr8,
                            int n, int nbk) {
    int b = blockIdx.x;
    int n0 = b << BSH;
    int n1 = min(n0 + BSZ, n);
    int bstart = offsets[n0];
    int bend   = offsets[n1];
    for (int i = bstart + threadIdx.x; i < bend; i += 256) {
        int2 r = binned[i];
        int d  = n0 + (r.y >> 18);
        int s  = r.y & 0x3FFFF;
        int pos = atomicAdd(&ncursor[d], 1);
        csr8[pos] = make_int2(s, r.x);   // (src, w bits)
    }
}

// ---------------- propagate: one wave per destination row, lane = column ----------------
// Edge loop batched by 16: 16 int2 csr loads, then 16 gathers outstanding, then FMA tail.
// If NORM: apply BatchNorm(scale,shift)+LeakyReLU to the gathered source value on the fly.

template <bool NORM>
__global__ void prop_kernel(const float* __restrict__ in, const float* __restrict__ ss,
                            const int* __restrict__ offsets, const int2* __restrict__ csr8,
                            float* __restrict__ out, int n) {
    int gid = blockIdx.x * 256 + threadIdx.x;
    int row  = gid >> 6;
    int lane = gid & 63;
    if (row >= n) return;
    int start = offsets[row];
    int end   = offsets[row + 1];
    float sc = 1.f, sh = 0.f;
    if (NORM) { sc = ss[lane]; sh = ss[64 + lane]; }
    float acc = 0.f;
    int i   = start;
    int deg = end - start;
    while (deg > 0) {
        int k = (deg < 16) ? deg : 16;   // wave-uniform
        int2 recs[16];
#pragma unroll
        for (int j = 0; j < 16; ++j) {
            if (j < k) recs[j] = csr8[i + j];
        }
        float vs[16];
#pragma unroll
        for (int j = 0; j < 16; ++j) {
            if (j < k) vs[j] = in[(size_t)recs[j].x * 64 + lane];
        }
#pragma unroll
        for (int j = 0; j < 16; ++j) {
            if (j < k) {
                float v = vs[j];
                if (NORM) {
                    v = fmaf(v, sc, sh);
                    v = (v >= 0.f) ? v : NEG_SLOPE * v;
                }
                acc = fmaf(v, __int_as_float(recs[j].y), acc);
            }
        }
        i   += k;
        deg -= k;
    }
    out[(size_t)row * 64 + lane] = acc;
}

// ---------------- dense linear: out[N,DOUT] = A[N,64] @ W[64,DOUT] + b ----------------

template <int DOUT>
__global__ void gemm_kernel(const float* __restrict__ A, const float* __restrict__ W,
                            const float* __restrict__ b, float* __restrict__ out, int n) {
    constexpr int C4  = DOUT / 4;      // float4 col-chunks per row
    constexpr int RPB = 256 / C4;      // rows per block
    __shared__ float Wl[64 * DOUT];
    for (int i = threadIdx.x; i < 64 * DOUT; i += 256) Wl[i] = W[i];
    __syncthreads();
    int rl  = threadIdx.x / C4;
    int c4  = threadIdx.x % C4;
    int row = blockIdx.x * RPB + rl;
    if (row >= n) return;
    float4 acc;
    acc.x = b[c4 * 4 + 0];
    acc.y = b[c4 * 4 + 1];
    acc.z = b[c4 * 4 + 2];
    acc.w = b[c4 * 4 + 3];
    const float4* A4 = reinterpret_cast<const float4*>(A + (size_t)row * 64);
#pragma unroll
    for (int k4 = 0; k4 < 16; ++k4) {
        float4 a4 = A4[k4];
#pragma unroll
        for (int j = 0; j < 4; ++j) {
            float a = (&a4.x)[j];
            const float* wp = &Wl[(k4 * 4 + j) * DOUT + c4 * 4];
            acc.x = fmaf(a, wp[0], acc.x);
            acc.y = fmaf(a, wp[1], acc.y);
            acc.z = fmaf(a, wp[2], acc.z);
            acc.w = fmaf(a, wp[3], acc.w);
        }
    }
    float4* o4 = reinterpret_cast<float4*>(out + (size_t)row * DOUT);
    o4[c4] = acc;
}

// ---------------- BatchNorm stats: per-column sum & sumsq (double) ----------------

__global__ void stats_kernel(const float* __restrict__ h, double* __restrict__ sums, int n) {
    int c  = threadIdx.x & 63;
    int rg = threadIdx.x >> 6;  // 0..3
    double s = 0.0, q = 0.0;
    for (int r = blockIdx.x * 4 + rg; r < n; r += gridDim.x * 4) {
        float v = h[(size_t)r * 64 + c];
        s += v;
        q += (double)v * v;
    }
    __shared__ double ls[4][64], lq[4][64];
    ls[rg][c] = s;
    lq[rg][c] = q;
    __syncthreads();
    if (threadIdx.x < 64) {
        double ts = ls[0][c] + ls[1][c] + ls[2][c] + ls[3][c];
        double tq = lq[0][c] + lq[1][c] + lq[2][c] + lq[3][c];
        atomicAdd(&sums[c], ts);
        atomicAdd(&sums[64 + c], tq);
    }
}

__global__ void bnfin_kernel(const double* __restrict__ sums, const float* __restrict__ g,
                             const float* __restrict__ be, float* __restrict__ ss, int n) {
    int c = threadIdx.x;
    if (c < 64) {
        double mean = sums[c] / n;
        double var  = sums[64 + c] / n - mean * mean;
        double inv  = 1.0 / sqrt(var + 1e-5);
        float scale = (float)(inv * (double)g[c]);
        ss[c]      = scale;
        ss[64 + c] = be[c] - (float)mean * scale;
    }
}

// ---------------- launch ----------------

extern "C" void kernel_launch(void* const* d_in, const int* in_sizes, int n_in,
                              void* d_out, int out_size, void* d_ws, size_t ws_size,
                              hipStream_t stream) {
    const float* x    = (const float*)d_in[0];
    const int*   ei   = (const int*)d_in[1];
    const float* ew   = (const float*)d_in[2];
    const float* W1   = (const float*)d_in[4];
    const float* b1   = (const float*)d_in[5];
    const float* g1   = (const float*)d_in[6];
    const float* be1  = (const float*)d_in[7];
    const float* W2   = (const float*)d_in[8];
    const float* b2   = (const float*)d_in[9];
    const float* g2   = (const float*)d_in[10];
    const float* be2  = (const float*)d_in[11];
    const float* W3   = (const float*)d_in[12];
    const float* b3   = (const float*)d_in[13];
    float* out = (float*)d_out;

    const int N = in_sizes[0] / 64;   // 100000
    const int E = in_sizes[2];        // 1000000
    const int* src = ei;
    const int* dst = ei + E;

    // workspace layout (256B aligned)
    char* wsb = (char*)d_ws;
    size_t off = 0;
    auto alloc = [&](size_t bytes) -> void* {
        off = (off + 255) & ~(size_t)255;
        void* p = wsb + off;
        off += bytes;
        return p;
    };
    float*  agg     = (float*)alloc((size_t)N * 64 * 4);
    float*  h       = (float*)alloc((size_t)N * 64 * 4);
    int2*   csr8    = (int2*)alloc((size_t)E * 8);
    int*    counts  = (int*)alloc((size_t)N * 4);
    int*    offsets = (int*)alloc((size_t)(N + 1) * 4);
    int*    cursor  = (int*)alloc((size_t)N * 4);
    int*    bsums   = (int*)alloc(1024 * 4);
    int*    bcursor = (int*)alloc((size_t)((N >> BSH) + 2) * 4);
    double* stats1  = (double*)alloc(128 * 8);
    double* stats2  = (double*)alloc(128 * 8);
    float*  ss1     = (float*)alloc(128 * 4);
    float*  ss2     = (float*)alloc(128 * 4);
    int2*   binned  = (int2*)h;   // alias: dead before gemm1 writes h
    (void)ws_size; (void)n_in; (void)out_size;

    hipMemsetAsync(counts, 0, (size_t)N * 4, stream);
    hipMemsetAsync(stats1, 0, 128 * 8, stream);
    hipMemsetAsync(stats2, 0, 128 * 8, stream);

    const int eblocks = (E + 255) / 256;
    const int pblocks = (N * 64 + 255) / 256;   // wave-per-row propagate
    const int gblocks64 = (N + 15) / 16;        // gemm DOUT=64: 16 rows/block
    const int gblocks32 = (N + 31) / 32;        // gemm DOUT=32: 32 rows/block
    const int nb  = (N + 1023) / 1024;          // scan blocks (98)
    const int nbk = (N + BSZ - 1) >> BSH;       // buckets (3125)

    // CSR build
    hist_kernel<<<eblocks, 256, 0, stream>>>(dst, counts, E);
    scan_bsum<<<nb, 256, 0, stream>>>(counts, bsums, N);
    scan_bsums<<<1, 128, 0, stream>>>(bsums, offsets, nb, N);
    scan_write<<<nb, 256, 0, stream>>>(counts, bsums, offsets, cursor, N);
    binit_kernel<<<(nbk + 255) / 256, 256, 0, stream>>>(offsets, bcursor, nbk);
    binA_kernel<<<eblocks, 256, 0, stream>>>(src, dst, ew, bcursor, binned, E);
    binB_kernel<<<nbk, 256, 0, stream>>>(offsets, cursor, binned, csr8, N, nbk);

    // layer 1
    prop_kernel<false><<<pblocks, 256, 0, stream>>>(x, nullptr, offsets, csr8, agg, N);
    gemm_kernel<64><<<gblocks64, 256, 0, stream>>>(agg, W1, b1, h, N);
    stats_kernel<<<256, 256, 0, stream>>>(h, stats1, N);
    bnfin_kernel<<<1, 64, 0, stream>>>(stats1, g1, be1, ss1, N);

    // layer 2 (BN+LeakyReLU of h fused into gather)
    prop_kernel<true><<<pblocks, 256, 0, stream>>>(h, ss1, offsets, csr8, agg, N);
    gemm_kernel<64><<<gblocks64, 256, 0, stream>>>(agg, W2, b2, h, N);
    stats_kernel<<<256, 256, 0, stream>>>(h, stats2, N);
    bnfin_kernel<<<1, 64, 0, stream>>>(stats2, g2, be2, ss2, N);

    // layer 3 (output, no norm)
    prop_kernel<true><<<pblocks, 256, 0, stream>>>(h, ss2, offsets, csr8, agg, N);
    gemm_kernel<32><<<gblocks32, 256, 0, stream>>>(agg, W3, b3, out, N);
}

// Round 5
// 378.386 us; speedup vs baseline: 1.1798x; 1.1798x over previous
//
#include <hip/hip_runtime.h>
#include <math.h>

#define NEG_SLOPE 0.01f

// ---------------- CSR build ----------------

__global__ void hist_kernel(const int* __restrict__ dst, int* __restrict__ counts, int E) {
    int e = blockIdx.x * 256 + threadIdx.x;
    if (e < E) atomicAdd(&counts[dst[e]], 1);
}

// ---- multi-block exclusive scan of counts[0..n) -> offsets/cursor; offsets[n]=total ----

__global__ void scan_bsum(const int* __restrict__ counts, int* __restrict__ bsums, int n) {
    int t = threadIdx.x;
    int i0 = blockIdx.x * 1024 + t * 4;
    int4 c;
    if (i0 + 3 < n) {
        c = *reinterpret_cast<const int4*>(counts + i0);
    } else {
        c.x = (i0 + 0 < n) ? counts[i0 + 0] : 0;
        c.y = (i0 + 1 < n) ? counts[i0 + 1] : 0;
        c.z = (i0 + 2 < n) ? counts[i0 + 2] : 0;
        c.w = (i0 + 3 < n) ? counts[i0 + 3] : 0;
    }
    int s = c.x + c.y + c.z + c.w;
#pragma unroll
    for (int d = 32; d > 0; d >>= 1) s += __shfl_down(s, d);
    __shared__ int wtot[4];
    if ((t & 63) == 0) wtot[t >> 6] = s;
    __syncthreads();
    if (t == 0) bsums[blockIdx.x] = wtot[0] + wtot[1] + wtot[2] + wtot[3];
}

__global__ void scan_bsums(int* __restrict__ bsums, int* __restrict__ offsets, int nb, int n) {
    __shared__ int lds[128];
    int t = threadIdx.x;
    int v = (t < nb) ? bsums[t] : 0;
    lds[t] = v;
    __syncthreads();
    for (int d = 1; d < 128; d <<= 1) {
        int u = (t >= d) ? lds[t - d] : 0;
        __syncthreads();
        lds[t] += u;
        __syncthreads();
    }
    if (t < nb) bsums[t] = lds[t] - v;   // exclusive block base
    if (t == 127) offsets[n] = lds[127]; // total
}

__global__ void scan_write(const int* __restrict__ counts, const int* __restrict__ bbase,
                           int* __restrict__ offsets, int* __restrict__ cursor, int n) {
    int t = threadIdx.x;
    int lane = t & 63, wid = t >> 6;
    int i0 = blockIdx.x * 1024 + t * 4;
    int4 c;
    if (i0 + 3 < n) {
        c = *reinterpret_cast<const int4*>(counts + i0);
    } else {
        c.x = (i0 + 0 < n) ? counts[i0 + 0] : 0;
        c.y = (i0 + 1 < n) ? counts[i0 + 1] : 0;
        c.z = (i0 + 2 < n) ? counts[i0 + 2] : 0;
        c.w = (i0 + 3 < n) ? counts[i0 + 3] : 0;
    }
    int s = c.x + c.y + c.z + c.w;
    int inc = s;
#pragma unroll
    for (int d = 1; d < 64; d <<= 1) {
        int v = __shfl_up(inc, d);
        if (lane >= d) inc += v;
    }
    __shared__ int wtot[4];
    if (lane == 63) wtot[wid] = inc;
    __syncthreads();
    int wbase = 0;
    for (int i = 0; i < wid; ++i) wbase += wtot[i];
    int excl = bbase[blockIdx.x] + wbase + inc - s;
    int o0 = excl, o1 = o0 + c.x, o2 = o1 + c.y, o3 = o2 + c.z;
    if (i0 + 3 < n) {
        int4 o = make_int4(o0, o1, o2, o3);
        *reinterpret_cast<int4*>(offsets + i0) = o;
        *reinterpret_cast<int4*>(cursor + i0)  = o;
    } else {
        if (i0 + 0 < n) { offsets[i0 + 0] = o0; cursor[i0 + 0] = o0; }
        if (i0 + 1 < n) { offsets[i0 + 1] = o1; cursor[i0 + 1] = o1; }
        if (i0 + 2 < n) { offsets[i0 + 2] = o2; cursor[i0 + 2] = o2; }
        if (i0 + 3 < n) { offsets[i0 + 3] = o3; cursor[i0 + 3] = o3; }
    }
}

// Direct fill: one packed 8B record per edge, scattered by per-node cursor
// (100k-way atomics -> low contention; single int2 store -> half the dirtied lines).
__global__ void fill_kernel(const int* __restrict__ src, const int* __restrict__ dst,
                            const float* __restrict__ w, int* __restrict__ cursor,
                            int2* __restrict__ csr8, int E) {
    int e = blockIdx.x * 256 + threadIdx.x;
    if (e < E) {
        int d = dst[e];
        int pos = atomicAdd(&cursor[d], 1);
        csr8[pos] = make_int2(src[e], __float_as_int(w[e]));
    }
}

// ---------------- propagate: one wave per destination row, lane = column ----------------
// Edge loop batched by 16: 16 int2 csr loads, then 16 gathers outstanding, then FMA tail.
// If NORM: apply BatchNorm(scale,shift)+LeakyReLU to the gathered source value on the fly.

template <bool NORM>
__global__ void prop_kernel(const float* __restrict__ in, const float* __restrict__ ss,
                            const int* __restrict__ offsets, const int2* __restrict__ csr8,
                            float* __restrict__ out, int n) {
    int gid = blockIdx.x * 256 + threadIdx.x;
    int row  = gid >> 6;
    int lane = gid & 63;
    if (row >= n) return;
    int start = offsets[row];
    int end   = offsets[row + 1];
    float sc = 1.f, sh = 0.f;
    if (NORM) { sc = ss[lane]; sh = ss[64 + lane]; }
    float acc = 0.f;
    int i   = start;
    int deg = end - start;
    while (deg > 0) {
        int k = (deg < 16) ? deg : 16;   // wave-uniform
        int2 recs[16];
#pragma unroll
        for (int j = 0; j < 16; ++j) {
            if (j < k) recs[j] = csr8[i + j];
        }
        float vs[16];
#pragma unroll
        for (int j = 0; j < 16; ++j) {
            if (j < k) vs[j] = in[(size_t)recs[j].x * 64 + lane];
        }
#pragma unroll
        for (int j = 0; j < 16; ++j) {
            if (j < k) {
                float v = vs[j];
                if (NORM) {
                    v = fmaf(v, sc, sh);
                    v = (v >= 0.f) ? v : NEG_SLOPE * v;
                }
                acc = fmaf(v, __int_as_float(recs[j].y), acc);
            }
        }
        i   += k;
        deg -= k;
    }
    out[(size_t)row * 64 + lane] = acc;
}

// ---------------- dense linear: out[N,DOUT] = A[N,64] @ W[64,DOUT] + b ----------------

template <int DOUT>
__global__ void gemm_kernel(const float* __restrict__ A, const float* __restrict__ W,
                            const float* __restrict__ b, float* __restrict__ out, int n) {
    constexpr int C4  = DOUT / 4;      // float4 col-chunks per row
    constexpr int RPB = 256 / C4;      // rows per block
    __shared__ float Wl[64 * DOUT];
    for (int i = threadIdx.x; i < 64 * DOUT; i += 256) Wl[i] = W[i];
    __syncthreads();
    int rl  = threadIdx.x / C4;
    int c4  = threadIdx.x % C4;
    int row = blockIdx.x * RPB + rl;
    if (row >= n) return;
    float4 acc;
    acc.x = b[c4 * 4 + 0];
    acc.y = b[c4 * 4 + 1];
    acc.z = b[c4 * 4 + 2];
    acc.w = b[c4 * 4 + 3];
    const float4* A4 = reinterpret_cast<const float4*>(A + (size_t)row * 64);
#pragma unroll
    for (int k4 = 0; k4 < 16; ++k4) {
        float4 a4 = A4[k4];
#pragma unroll
        for (int j = 0; j < 4; ++j) {
            float a = (&a4.x)[j];
            const float* wp = &Wl[(k4 * 4 + j) * DOUT + c4 * 4];
            acc.x = fmaf(a, wp[0], acc.x);
            acc.y = fmaf(a, wp[1], acc.y);
            acc.z = fmaf(a, wp[2], acc.z);
            acc.w = fmaf(a, wp[3], acc.w);
        }
    }
    float4* o4 = reinterpret_cast<float4*>(out + (size_t)row * DOUT);
    o4[c4] = acc;
}

// ---------------- BatchNorm stats: per-column sum & sumsq (double) ----------------

__global__ void stats_kernel(const float* __restrict__ h, double* __restrict__ sums, int n) {
    int c  = threadIdx.x & 63;
    int rg = threadIdx.x >> 6;  // 0..3
    double s = 0.0, q = 0.0;
    for (int r = blockIdx.x * 4 + rg; r < n; r += gridDim.x * 4) {
        float v = h[(size_t)r * 64 + c];
        s += v;
        q += (double)v * v;
    }
    __shared__ double ls[4][64], lq[4][64];
    ls[rg][c] = s;
    lq[rg][c] = q;
    __syncthreads();
    if (threadIdx.x < 64) {
        double ts = ls[0][c] + ls[1][c] + ls[2][c] + ls[3][c];
        double tq = lq[0][c] + lq[1][c] + lq[2][c] + lq[3][c];
        atomicAdd(&sums[c], ts);
        atomicAdd(&sums[64 + c], tq);
    }
}

__global__ void bnfin_kernel(const double* __restrict__ sums, const float* __restrict__ g,
                             const float* __restrict__ be, float* __restrict__ ss, int n) {
    int c = threadIdx.x;
    if (c < 64) {
        double mean = sums[c] / n;
        double var  = sums[64 + c] / n - mean * mean;
        double inv  = 1.0 / sqrt(var + 1e-5);
        float scale = (float)(inv * (double)g[c]);
        ss[c]      = scale;
        ss[64 + c] = be[c] - (float)mean * scale;
    }
}

// ---------------- launch ----------------

extern "C" void kernel_launch(void* const* d_in, const int* in_sizes, int n_in,
                              void* d_out, int out_size, void* d_ws, size_t ws_size,
                              hipStream_t stream) {
    const float* x    = (const float*)d_in[0];
    const int*   ei   = (const int*)d_in[1];
    const float* ew   = (const float*)d_in[2];
    const float* W1   = (const float*)d_in[4];
    const float* b1   = (const float*)d_in[5];
    const float* g1   = (const float*)d_in[6];
    const float* be1  = (const float*)d_in[7];
    const float* W2   = (const float*)d_in[8];
    const float* b2   = (const float*)d_in[9];
    const float* g2   = (const float*)d_in[10];
    const float* be2  = (const float*)d_in[11];
    const float* W3   = (const float*)d_in[12];
    const float* b3   = (const float*)d_in[13];
    float* out = (float*)d_out;

    const int N = in_sizes[0] / 64;   // 100000
    const int E = in_sizes[2];        // 1000000
    const int* src = ei;
    const int* dst = ei + E;

    // workspace layout (256B aligned)
    char* wsb = (char*)d_ws;
    size_t off = 0;
    auto alloc = [&](size_t bytes) -> void* {
        off = (off + 255) & ~(size_t)255;
        void* p = wsb + off;
        off += bytes;
        return p;
    };
    float*  agg     = (float*)alloc((size_t)N * 64 * 4);
    float*  h       = (float*)alloc((size_t)N * 64 * 4);
    int2*   csr8    = (int2*)alloc((size_t)E * 8);
    // counts + stats1 + stats2 contiguous -> single memset
    char*   zblock  = (char*)alloc((size_t)N * 4 + 2048);
    int*    counts  = (int*)zblock;
    double* stats1  = (double*)(zblock + (size_t)N * 4);          // N*4 % 8 == 0
    double* stats2  = stats1 + 128;
    int*    offsets = (int*)alloc((size_t)(N + 1) * 4);
    int*    cursor  = (int*)alloc((size_t)N * 4);
    int*    bsums   = (int*)alloc(1024 * 4);
    float*  ss1     = (float*)alloc(128 * 4);
    float*  ss2     = (float*)alloc(128 * 4);
    (void)ws_size; (void)n_in; (void)out_size;

    hipMemsetAsync(zblock, 0, (size_t)N * 4 + 2048, stream);

    const int eblocks = (E + 255) / 256;
    const int pblocks = (N * 64 + 255) / 256;   // wave-per-row propagate
    const int gblocks64 = (N + 15) / 16;        // gemm DOUT=64: 16 rows/block
    const int gblocks32 = (N + 31) / 32;        // gemm DOUT=32: 32 rows/block
    const int nb = (N + 1023) / 1024;           // scan blocks (98)

    // CSR build
    hist_kernel<<<eblocks, 256, 0, stream>>>(dst, counts, E);
    scan_bsum<<<nb, 256, 0, stream>>>(counts, bsums, N);
    scan_bsums<<<1, 128, 0, stream>>>(bsums, offsets, nb, N);
    scan_write<<<nb, 256, 0, stream>>>(counts, bsums, offsets, cursor, N);
    fill_kernel<<<eblocks, 256, 0, stream>>>(src, dst, ew, cursor, csr8, E);

    // layer 1
    prop_kernel<false><<<pblocks, 256, 0, stream>>>(x, nullptr, offsets, csr8, agg, N);
    gemm_kernel<64><<<gblocks64, 256, 0, stream>>>(agg, W1, b1, h, N);
    stats_kernel<<<256, 256, 0, stream>>>(h, stats1, N);
    bnfin_kernel<<<1, 64, 0, stream>>>(stats1, g1, be1, ss1, N);

    // layer 2 (BN+LeakyReLU of h fused into gather)
    prop_kernel<true><<<pblocks, 256, 0, stream>>>(h, ss1, offsets, csr8, agg, N);
    gemm_kernel<64><<<gblocks64, 256, 0, stream>>>(agg, W2, b2, h, N);
    stats_kernel<<<256, 256, 0, stream>>>(h, stats2, N);
    bnfin_kernel<<<1, 64, 0, stream>>>(stats2, g2, be2, ss2, N);

    // layer 3 (output, no norm)
    prop_kernel<true><<<pblocks, 256, 0, stream>>>(h, ss2, offsets, csr8, agg, N);
    gemm_kernel<32><<<gblocks32, 256, 0, stream>>>(agg, W3, b3, out, N);
}

// Round 6
// 297.879 us; speedup vs baseline: 1.4987x; 1.2703x over previous
//
#include <hip/hip_runtime.h>
#include <math.h>

#define NEG_SLOPE 0.01f
#define NBLK 256        // partition blocks for A1/A2
#define BND  256        // nodes per bucket

// ================= CSR build: two-level counting sort, no global atomics ==========

// A1: per-(block,bucket) histogram. cmat[bucket*NBLK + blk].
__global__ void partA1(const int* __restrict__ dst, int* __restrict__ cmat,
                       int E, int epb, int nbk) {
    __shared__ int cnt[512];
    for (int i = threadIdx.x; i < 512; i += 512) cnt[i] = 0;
    __syncthreads();
    int b = blockIdx.x;
    int e0 = b * epb, e1 = min(e0 + epb, E);
    for (int e = e0 + threadIdx.x; e < e1; e += 512)
        atomicAdd(&cnt[dst[e] >> 8], 1);          // LDS atomic
    __syncthreads();
    for (int k = threadIdx.x; k < nbk; k += 512)
        cmat[k * NBLK + b] = cnt[k];
}

// ---- multi-block exclusive scan over cmat (M = nbk*NBLK elements) ----

__global__ void scan_bsum(const int* __restrict__ in, int* __restrict__ bsums, int n) {
    int t = threadIdx.x;
    int i0 = blockIdx.x * 1024 + t * 4;
    int4 c;
    if (i0 + 3 < n) {
        c = *reinterpret_cast<const int4*>(in + i0);
    } else {
        c.x = (i0 + 0 < n) ? in[i0 + 0] : 0;
        c.y = (i0 + 1 < n) ? in[i0 + 1] : 0;
        c.z = (i0 + 2 < n) ? in[i0 + 2] : 0;
        c.w = (i0 + 3 < n) ? in[i0 + 3] : 0;
    }
    int s = c.x + c.y + c.z + c.w;
#pragma unroll
    for (int d = 32; d > 0; d >>= 1) s += __shfl_down(s, d);
    __shared__ int wtot[4];
    if ((t & 63) == 0) wtot[t >> 6] = s;
    __syncthreads();
    if (t == 0) bsums[blockIdx.x] = wtot[0] + wtot[1] + wtot[2] + wtot[3];
}

__global__ void scan_bsums(int* __restrict__ bsums, int* __restrict__ outx, int nb, int n) {
    __shared__ int lds[128];
    int t = threadIdx.x;
    int v = (t < nb) ? bsums[t] : 0;
    lds[t] = v;
    __syncthreads();
    for (int d = 1; d < 128; d <<= 1) {
        int u = (t >= d) ? lds[t - d] : 0;
        __syncthreads();
        lds[t] += u;
        __syncthreads();
    }
    if (t < nb) bsums[t] = lds[t] - v;   // exclusive block base
    if (t == 127) outx[n] = lds[127];    // total (= E)
}

__global__ void scan_excl(const int* __restrict__ in, const int* __restrict__ bbase,
                          int* __restrict__ outx, int n) {
    int t = threadIdx.x;
    int lane = t & 63, wid = t >> 6;
    int i0 = blockIdx.x * 1024 + t * 4;
    int4 c;
    if (i0 + 3 < n) {
        c = *reinterpret_cast<const int4*>(in + i0);
    } else {
        c.x = (i0 + 0 < n) ? in[i0 + 0] : 0;
        c.y = (i0 + 1 < n) ? in[i0 + 1] : 0;
        c.z = (i0 + 2 < n) ? in[i0 + 2] : 0;
        c.w = (i0 + 3 < n) ? in[i0 + 3] : 0;
    }
    int s = c.x + c.y + c.z + c.w;
    int inc = s;
#pragma unroll
    for (int d = 1; d < 64; d <<= 1) {
        int v = __shfl_up(inc, d);
        if (lane >= d) inc += v;
    }
    __shared__ int wtot[4];
    if (lane == 63) wtot[wid] = inc;
    __syncthreads();
    int wbase = 0;
    for (int i = 0; i < wid; ++i) wbase += wtot[i];
    int excl = bbase[blockIdx.x] + wbase + inc - s;
    int o0 = excl, o1 = o0 + c.x, o2 = o1 + c.y, o3 = o2 + c.z;
    if (i0 + 3 < n) {
        *reinterpret_cast<int4*>(outx + i0) = make_int4(o0, o1, o2, o3);
    } else {
        if (i0 + 0 < n) outx[i0 + 0] = o0;
        if (i0 + 1 < n) outx[i0 + 1] = o1;
        if (i0 + 2 < n) outx[i0 + 2] = o2;
        if (i0 + 3 < n) outx[i0 + 3] = o3;
    }
}

// A2: place records into bucket-ordered 'binned' via LDS cursors (no global atomics).
// Record: .x = w bits, .y = src | dloc<<18  (src < 2^18, dloc < 256).
__global__ void partA2(const int* __restrict__ src, const int* __restrict__ dst,
                       const float* __restrict__ w, const int* __restrict__ cbase,
                       int2* __restrict__ binned, int E, int epb, int nbk) {
    __shared__ int cur[512];
    int b = blockIdx.x;
    for (int k = threadIdx.x; k < nbk; k += 512) cur[k] = cbase[k * NBLK + b];
    __syncthreads();
    int e0 = b * epb, e1 = min(e0 + epb, E);
    for (int e = e0 + threadIdx.x; e < e1; e += 512) {
        int d = dst[e];
        int pos = atomicAdd(&cur[d >> 8], 1);     // LDS atomic, returning
        binned[pos] = make_int2(__float_as_int(w[e]), src[e] | ((d & 255) << 18));
    }
}

// B: one block per bucket. Per-node count + LDS scan -> offsets window; then exact
// placement into the bucket's contiguous csr8 window (L2-combined full-line writes).
__global__ void partB(const int* __restrict__ cbase, const int2* __restrict__ binned,
                      int2* __restrict__ csr8, int* __restrict__ offsets,
                      int N, int E, int nbk) {
    __shared__ int lcnt[256], lofs[256];
    int b = blockIdx.x;
    int t = threadIdx.x;
    lcnt[t] = 0;
    __syncthreads();
    int bstart = cbase[b * NBLK];
    int bend   = cbase[(b + 1) * NBLK];   // for b==nbk-1 this is cbase[M]=E
    for (int i = bstart + t; i < bend; i += 256)
        atomicAdd(&lcnt[(binned[i].y >> 18) & 255], 1);
    __syncthreads();
    int v = lcnt[t];
    lofs[t] = v;
    __syncthreads();
    for (int d = 1; d < 256; d <<= 1) {
        int u = (t >= d) ? lofs[t - d] : 0;
        __syncthreads();
        lofs[t] += u;
        __syncthreads();
    }
    int excl = lofs[t] - v;
    int node = (b << 8) + t;
    if (node < N) offsets[node] = bstart + excl;
    if (b == nbk - 1 && t == 0) offsets[N] = E;
    __syncthreads();
    lcnt[t] = bstart + excl;              // reuse as cursor
    __syncthreads();
    for (int i = bstart + t; i < bend; i += 256) {
        int2 r = binned[i];
        int pos = atomicAdd(&lcnt[(r.y >> 18) & 255], 1);
        csr8[pos] = make_int2(r.y & 0x3FFFF, r.x);   // (src, w bits)
    }
}

// ---------------- propagate: one wave per destination row, lane = column ----------------

template <bool NORM>
__global__ void prop_kernel(const float* __restrict__ in, const float* __restrict__ ss,
                            const int* __restrict__ offsets, const int2* __restrict__ csr8,
                            float* __restrict__ out, int n) {
    int gid = blockIdx.x * 256 + threadIdx.x;
    int row  = gid >> 6;
    int lane = gid & 63;
    if (row >= n) return;
    int start = offsets[row];
    int end   = offsets[row + 1];
    float sc = 1.f, sh = 0.f;
    if (NORM) { sc = ss[lane]; sh = ss[64 + lane]; }
    float acc = 0.f;
    int i   = start;
    int deg = end - start;
    while (deg > 0) {
        int k = (deg < 16) ? deg : 16;   // wave-uniform
        int2 recs[16];
#pragma unroll
        for (int j = 0; j < 16; ++j) {
            if (j < k) recs[j] = csr8[i + j];
        }
        float vs[16];
#pragma unroll
        for (int j = 0; j < 16; ++j) {
            if (j < k) vs[j] = in[(size_t)recs[j].x * 64 + lane];
        }
#pragma unroll
        for (int j = 0; j < 16; ++j) {
            if (j < k) {
                float v = vs[j];
                if (NORM) {
                    v = fmaf(v, sc, sh);
                    v = (v >= 0.f) ? v : NEG_SLOPE * v;
                }
                acc = fmaf(v, __int_as_float(recs[j].y), acc);
            }
        }
        i   += k;
        deg -= k;
    }
    out[(size_t)row * 64 + lane] = acc;
}

// ---------------- dense linear: out[N,DOUT] = A[N,64] @ W[64,DOUT] + b ----------------

template <int DOUT>
__global__ void gemm_kernel(const float* __restrict__ A, const float* __restrict__ W,
                            const float* __restrict__ b, float* __restrict__ out, int n) {
    constexpr int C4  = DOUT / 4;
    constexpr int RPB = 256 / C4;
    __shared__ float Wl[64 * DOUT];
    for (int i = threadIdx.x; i < 64 * DOUT; i += 256) Wl[i] = W[i];
    __syncthreads();
    int rl  = threadIdx.x / C4;
    int c4  = threadIdx.x % C4;
    int row = blockIdx.x * RPB + rl;
    if (row >= n) return;
    float4 acc;
    acc.x = b[c4 * 4 + 0];
    acc.y = b[c4 * 4 + 1];
    acc.z = b[c4 * 4 + 2];
    acc.w = b[c4 * 4 + 3];
    const float4* A4 = reinterpret_cast<const float4*>(A + (size_t)row * 64);
#pragma unroll
    for (int k4 = 0; k4 < 16; ++k4) {
        float4 a4 = A4[k4];
#pragma unroll
        for (int j = 0; j < 4; ++j) {
            float a = (&a4.x)[j];
            const float* wp = &Wl[(k4 * 4 + j) * DOUT + c4 * 4];
            acc.x = fmaf(a, wp[0], acc.x);
            acc.y = fmaf(a, wp[1], acc.y);
            acc.z = fmaf(a, wp[2], acc.z);
            acc.w = fmaf(a, wp[3], acc.w);
        }
    }
    float4* o4 = reinterpret_cast<float4*>(out + (size_t)row * DOUT);
    o4[c4] = acc;
}

// ---------------- BatchNorm stats: per-column sum & sumsq (double) ----------------

__global__ void stats_kernel(const float* __restrict__ h, double* __restrict__ sums, int n) {
    int c  = threadIdx.x & 63;
    int rg = threadIdx.x >> 6;
    double s = 0.0, q = 0.0;
    for (int r = blockIdx.x * 4 + rg; r < n; r += gridDim.x * 4) {
        float v = h[(size_t)r * 64 + c];
        s += v;
        q += (double)v * v;
    }
    __shared__ double ls[4][64], lq[4][64];
    ls[rg][c] = s;
    lq[rg][c] = q;
    __syncthreads();
    if (threadIdx.x < 64) {
        double ts = ls[0][c] + ls[1][c] + ls[2][c] + ls[3][c];
        double tq = lq[0][c] + lq[1][c] + lq[2][c] + lq[3][c];
        atomicAdd(&sums[c], ts);
        atomicAdd(&sums[64 + c], tq);
    }
}

__global__ void bnfin_kernel(const double* __restrict__ sums, const float* __restrict__ g,
                             const float* __restrict__ be, float* __restrict__ ss, int n) {
    int c = threadIdx.x;
    if (c < 64) {
        double mean = sums[c] / n;
        double var  = sums[64 + c] / n - mean * mean;
        double inv  = 1.0 / sqrt(var + 1e-5);
        float scale = (float)(inv * (double)g[c]);
        ss[c]      = scale;
        ss[64 + c] = be[c] - (float)mean * scale;
    }
}

// ---------------- launch ----------------

extern "C" void kernel_launch(void* const* d_in, const int* in_sizes, int n_in,
                              void* d_out, int out_size, void* d_ws, size_t ws_size,
                              hipStream_t stream) {
    const float* x    = (const float*)d_in[0];
    const int*   ei   = (const int*)d_in[1];
    const float* ew   = (const float*)d_in[2];
    const float* W1   = (const float*)d_in[4];
    const float* b1   = (const float*)d_in[5];
    const float* g1   = (const float*)d_in[6];
    const float* be1  = (const float*)d_in[7];
    const float* W2   = (const float*)d_in[8];
    const float* b2   = (const float*)d_in[9];
    const float* g2   = (const float*)d_in[10];
    const float* be2  = (const float*)d_in[11];
    const float* W3   = (const float*)d_in[12];
    const float* b3   = (const float*)d_in[13];
    float* out = (float*)d_out;

    const int N = in_sizes[0] / 64;   // 100000
    const int E = in_sizes[2];        // 1000000
    const int* src = ei;
    const int* dst = ei + E;

    const int nbk = (N + BND - 1) / BND;        // 391 buckets
    const int M   = nbk * NBLK;                 // cmat elements (100096)
    const int epb = (E + NBLK - 1) / NBLK;      // edges per partition block

    // workspace layout (256B aligned)
    char* wsb = (char*)d_ws;
    size_t off = 0;
    auto alloc = [&](size_t bytes) -> void* {
        off = (off + 255) & ~(size_t)255;
        void* p = wsb + off;
        off += bytes;
        return p;
    };
    float*  agg     = (float*)alloc((size_t)N * 64 * 4);
    float*  h       = (float*)alloc((size_t)N * 64 * 4);
    int2*   csr8    = (int2*)alloc((size_t)E * 8);
    int*    cmat    = (int*)alloc((size_t)M * 4);
    int*    cbase   = (int*)alloc((size_t)(M + 1) * 4);
    int*    offsets = (int*)alloc((size_t)(N + 1) * 4);
    int*    bsums   = (int*)alloc(1024 * 4);
    char*   zblock  = (char*)alloc(2048);       // stats1+stats2
    double* stats1  = (double*)zblock;
    double* stats2  = stats1 + 128;
    float*  ss1     = (float*)alloc(128 * 4);
    float*  ss2     = (float*)alloc(128 * 4);
    int2*   binned  = (int2*)h;                 // alias: dead before gemm1 writes h
    (void)ws_size; (void)n_in; (void)out_size;

    hipMemsetAsync(zblock, 0, 2048, stream);

    const int pblocks = (N * 64 + 255) / 256;
    const int gblocks64 = (N + 15) / 16;
    const int gblocks32 = (N + 31) / 32;
    const int nbM = (M + 1023) / 1024;          // 98 scan blocks

    // CSR build (atomic-free counting sort)
    partA1<<<NBLK, 512, 0, stream>>>(dst, cmat, E, epb, nbk);
    scan_bsum<<<nbM, 256, 0, stream>>>(cmat, bsums, M);
    scan_bsums<<<1, 128, 0, stream>>>(bsums, cbase, nbM, M);   // also cbase[M]=E
    scan_excl<<<nbM, 256, 0, stream>>>(cmat, bsums, cbase, M);
    partA2<<<NBLK, 512, 0, stream>>>(src, dst, ew, cbase, binned, E, epb, nbk);
    partB<<<nbk, 256, 0, stream>>>(cbase, binned, csr8, offsets, N, E, nbk);

    // layer 1
    prop_kernel<false><<<pblocks, 256, 0, stream>>>(x, nullptr, offsets, csr8, agg, N);
    gemm_kernel<64><<<gblocks64, 256, 0, stream>>>(agg, W1, b1, h, N);
    stats_kernel<<<256, 256, 0, stream>>>(h, stats1, N);
    bnfin_kernel<<<1, 64, 0, stream>>>(stats1, g1, be1, ss1, N);

    // layer 2 (BN+LeakyReLU of h fused into gather)
    prop_kernel<true><<<pblocks, 256, 0, stream>>>(h, ss1, offsets, csr8, agg, N);
    gemm_kernel<64><<<gblocks64, 256, 0, stream>>>(agg, W2, b2, h, N);
    stats_kernel<<<256, 256, 0, stream>>>(h, stats2, N);
    bnfin_kernel<<<1, 64, 0, stream>>>(stats2, g2, be2, ss2, N);

    // layer 3 (output, no norm)
    prop_kernel<true><<<pblocks, 256, 0, stream>>>(h, ss2, offsets, csr8, agg, N);
    gemm_kernel<32><<<gblocks32, 256, 0, stream>>>(agg, W3, b3, out, N);
}